// Round 4
// baseline (112.085 us; speedup 1.0000x reference)
//
#include <hip/hip_runtime.h>
#include <math.h>
#include <limits.h>

// Problem constants (fixed by reference setup_inputs)
constexpr int N = 8;
constexpr int H = 256;
constexpr int W = 256;
constexpr int NPIX = N * H * W;          // 524288
constexpr float FEPS = 1e-6f;
constexpr int   RSENT = 20000;           // row-empty sentinel: RSENT^2=4e8 >> legit max 130050
constexpr int   EMPTY_THRESH = 300000000;// > legit max 130050, < RSENT^2
constexpr int   NBLK2 = N * H;           // 2048 main-pass blocks (one per output row)

// ws layout:
//   short2 d1[N*H*W]        : (r_fg, r_bg) per pixel = 2 MB
//   float  parts[5][NBLK2]  : q=0: p*t, 1: p, 2: t, 3: phi*p, 4: focal
//   int    counter          : last-block election (zeroed by row_scan block 0)

// -------- Kernel 1: exact 1D row distance via parallel min-scans --------
// r_fg[px] = min over fg qx of |px-qx|  (RSENT if row has no fg); same for bg.
__global__ __launch_bounds__(256) void row_scan_kernel(
    const float* __restrict__ tgt, short2* __restrict__ d1, int* __restrict__ counter)
{
    const int b    = blockIdx.x;         // n*H + qy
    const int px   = threadIdx.x;
    const int lane = px & 63;
    const int wid  = px >> 6;
    const int BIG  = 1 << 20;

    if (b == 0 && px == 0) *counter = 0; // zero election counter for main_pass (runs after us)

    const float tv = tgt[b * W + px];
    const bool  fg = tv > 0.5f;
    const int cf = fg ? 0 : BIG;         // cost for fg-distance
    const int cb = fg ? BIG : 0;         // cost for bg-distance

    __shared__ int sm[8];                // per-wave (fg,bg) partials

    // ---- prefix phase: fwd[i] = i + min_{j<=i} (cost_j - j) ----
    int a = cf - px, c = cb - px;
    #pragma unroll
    for (int off = 1; off < 64; off <<= 1) {
        const int ua = __shfl_up(a, off, 64);
        const int uc = __shfl_up(c, off, 64);
        if (lane >= off) { a = min(a, ua); c = min(c, uc); }
    }
    if (lane == 63) { sm[wid * 2] = a; sm[wid * 2 + 1] = c; }
    __syncthreads();
    #pragma unroll
    for (int w = 0; w < 3; ++w) {
        if (w < wid) { a = min(a, sm[w * 2]); c = min(c, sm[w * 2 + 1]); }
    }
    const int fwd_fg = px + a;
    const int fwd_bg = px + c;
    __syncthreads();

    // ---- suffix phase: bwd[i] = -i + min_{j>=i} (cost_j + j) ----
    int a2 = cf + px, c2 = cb + px;
    #pragma unroll
    for (int off = 1; off < 64; off <<= 1) {
        const int ua = __shfl_down(a2, off, 64);
        const int uc = __shfl_down(c2, off, 64);
        if (lane + off < 64) { a2 = min(a2, ua); c2 = min(c2, uc); }
    }
    if (lane == 0) { sm[wid * 2] = a2; sm[wid * 2 + 1] = c2; }
    __syncthreads();
    #pragma unroll
    for (int w = 1; w < 4; ++w) {
        if (w > wid) { a2 = min(a2, sm[w * 2]); c2 = min(c2, sm[w * 2 + 1]); }
    }
    const int bwd_fg = a2 - px;
    const int bwd_bg = c2 - px;

    int rf = min(fwd_fg, bwd_fg); if (rf > 255) rf = RSENT;
    int rb = min(fwd_bg, bwd_bg); if (rb > 255) rb = RSENT;
    d1[b * W + px] = make_short2((short)rf, (short)rb);
}

// -------- Kernel 2: outward column scan w/ early exit + loss + reduce + finalize --------
__global__ __launch_bounds__(256) void main_pass_kernel(
    const float* __restrict__ pred, const float* __restrict__ tgt,
    const short2* __restrict__ d1, float* __restrict__ parts,
    int* __restrict__ counter, float* __restrict__ out)
{
    const int blk  = blockIdx.x;             // n*H + py
    const int n    = blk >> 8;
    const int py   = blk & 255;
    const int px   = threadIdx.x;
    const int lane = threadIdx.x & 63;
    const int wid  = threadIdx.x >> 6;
    const int idx  = blk * W + px;

    // issue the loss-term loads early (independent of the scan)
    const float x = pred[idx];
    const float t = tgt[idx];

    // exact column pass with early termination:
    //   best = min over |qy-py|<=delta of (qy-py)^2 + r[qy]^2;
    //   any qy beyond delta contributes >= delta^2, so stop once
    //   delta^2 >= best (both transforms, all lanes in the wave).
    const short2* __restrict__ img = d1 + (size_t)n * (H * W) + px;
    int best_f = INT_MAX, best_b = INT_MAX;
    for (int dlt = 0; dlt < H; ++dlt) {
        const int d2 = dlt * dlt;
        if (!__any((d2 < best_f) || (d2 < best_b))) break;
        const int up = py - dlt;
        const int dn = py + dlt;
        if (up >= 0) {
            const short2 r = img[up * W];
            best_f = min(best_f, (int)r.x * (int)r.x + d2);
            best_b = min(best_b, (int)r.y * (int)r.y + d2);
        }
        if (dn < H && dlt > 0) {
            const short2 r = img[dn * W];
            best_f = min(best_f, (int)r.x * (int)r.x + d2);
            best_b = min(best_b, (int)r.y * (int)r.y + d2);
        }
        if (up < 0 && dn >= H) break;
    }

    const float MAXD2 = (float)((H - 1) * (H - 1) + (W - 1) * (W - 1));
    const float Dfg = (best_f > EMPTY_THRESH) ? MAXD2 : (float)best_f;
    const float Dbg = (best_b > EMPTY_THRESH) ? MAXD2 : (float)best_b;

    const float p   = 1.0f / (1.0f + expf(-x));
    const float phi = (t > 0.5f) ? -sqrtf(Dbg) : sqrtf(Dfg);

    const float pc = fminf(fmaxf(p, FEPS), 1.0f - FEPS);
    const float pt = pc * t + (1.0f - pc) * (1.0f - t);
    const float at = 0.25f * t + 0.75f * (1.0f - t);
    const float om = 1.0f - pt;
    const float focal = -at * om * om * logf(pt);

    // block reduction of the 5 partials
    float v5[5] = { p * t, p, t, phi * p, focal };
    __shared__ float smem[4 * 5];
    #pragma unroll
    for (int q = 0; q < 5; ++q) {
        float v = v5[q];
        #pragma unroll
        for (int off = 32; off > 0; off >>= 1) v += __shfl_down(v, off, 64);
        v5[q] = v;
    }
    if (lane == 0) {
        #pragma unroll
        for (int q = 0; q < 5; ++q) smem[wid * 5 + q] = v5[q];
    }
    __syncthreads();
    if (threadIdx.x == 0) {
        #pragma unroll
        for (int q = 0; q < 5; ++q) {
            parts[q * NBLK2 + blk] = smem[q] + smem[5 + q] + smem[10 + q] + smem[15 + q];
        }
    }

    // ---- last-block election ----
    __shared__ int is_last;
    if (threadIdx.x == 0) {
        __threadfence();                        // make parts visible device-wide
        const int old = atomicAdd(counter, 1);
        is_last = (old == NBLK2 - 1) ? 1 : 0;
    }
    __syncthreads();
    if (!is_last) return;
    __threadfence();                            // acquire: see all blocks' parts

    // ---- finalize (one block, 256 threads) ----
    const int tid = threadIdx.x;
    __shared__ float smf[8];
    __shared__ float sratio[8];

    // boundary + focal: global sums over all NBLK2 partials
    float bp = 0.0f, fc = 0.0f;
    for (int k = tid; k < NBLK2; k += 256) {
        bp += parts[3 * NBLK2 + k];
        fc += parts[4 * NBLK2 + k];
    }
    #pragma unroll
    for (int off = 32; off > 0; off >>= 1) {
        bp += __shfl_down(bp, off, 64);
        fc += __shfl_down(fc, off, 64);
    }
    if (lane == 0) { smf[wid * 2] = bp; smf[wid * 2 + 1] = fc; }

    // dice: each wave handles 2 images (256 partials each)
    #pragma unroll
    for (int mi = 0; mi < 2; ++mi) {
        const int m = wid * 2 + mi;
        float A = 0.f, S = 0.f, C = 0.f;
        #pragma unroll
        for (int k = 0; k < 4; ++k) {
            const int i = m * 256 + k * 64 + lane;
            A += parts[0 * NBLK2 + i];
            S += parts[1 * NBLK2 + i];
            C += parts[2 * NBLK2 + i];
        }
        #pragma unroll
        for (int off = 32; off > 0; off >>= 1) {
            A += __shfl_down(A, off, 64);
            S += __shfl_down(S, off, 64);
            C += __shfl_down(C, off, 64);
        }
        if (lane == 0) sratio[m] = (2.0f * A + FEPS) / (S + C + FEPS);
    }
    __syncthreads();
    if (tid == 0) {
        const float B = smf[0] + smf[2] + smf[4] + smf[6];
        const float F = smf[1] + smf[3] + smf[5] + smf[7];
        float dacc = 0.0f;
        #pragma unroll
        for (int m = 0; m < 8; ++m) dacc += sratio[m];
        const float dice_val     = 1.0f - dacc / (float)N;
        const float boundary_val = B / (float)NPIX;
        const float focal_val    = F / (float)NPIX;
        out[0] = dice_val + boundary_val + focal_val;   // loss
        out[1] = dice_val;
        out[2] = boundary_val;
        out[3] = focal_val;
    }
}

extern "C" void kernel_launch(void* const* d_in, const int* in_sizes, int n_in,
                              void* d_out, int out_size, void* d_ws, size_t ws_size,
                              hipStream_t stream)
{
    const float* pred = (const float*)d_in[0];
    const float* tgt  = (const float*)d_in[1];
    float* out = (float*)d_out;

    short2* d1      = (short2*)d_ws;                                // 2 MB
    float*  parts   = (float*)((char*)d_ws + (size_t)NPIX * sizeof(short2));
    int*    counter = (int*)(parts + 5 * NBLK2);

    row_scan_kernel<<<N * H, 256, 0, stream>>>(tgt, d1, counter);
    main_pass_kernel<<<NBLK2, 256, 0, stream>>>(pred, tgt, d1, parts, counter, out);
}

// Round 5
// 72.554 us; speedup vs baseline: 1.5448x; 1.5448x over previous
//
#include <hip/hip_runtime.h>
#include <math.h>
#include <limits.h>

// Problem constants (fixed by reference setup_inputs)
constexpr int N = 8;
constexpr int H = 256;
constexpr int W = 256;
constexpr int NPIX = N * H * W;          // 524288
constexpr float FEPS = 1e-6f;
constexpr int   RSENT = 20000;           // row-empty sentinel: RSENT^2=4e8 >> legit max 130050
constexpr int   EMPTY_THRESH = 300000000;// > legit max 130050, < RSENT^2
constexpr int   NBLK2 = N * H;           // 2048 main-pass blocks (one per output row)
constexpr int   WIN = 3;                 // preloaded column window: qy in [py-WIN, py+WIN]

// ws layout:
//   short2 d1[N*H*W]        : (r_fg, r_bg) per pixel = 2 MB
//   float  parts[5][NBLK2]  : q=0: p*t, 1: p, 2: t, 3: phi*p, 4: focal

// -------- Kernel 1: exact 1D row distance via parallel min-scans --------
// r_fg[px] = min over fg qx of |px-qx|  (RSENT if row has no fg); same for bg.
__global__ __launch_bounds__(256) void row_scan_kernel(
    const float* __restrict__ tgt, short2* __restrict__ d1)
{
    const int b    = blockIdx.x;         // n*H + qy
    const int px   = threadIdx.x;
    const int lane = px & 63;
    const int wid  = px >> 6;
    const int BIG  = 1 << 20;

    const float tv = tgt[b * W + px];
    const bool  fg = tv > 0.5f;
    const int cf = fg ? 0 : BIG;         // cost for fg-distance
    const int cb = fg ? BIG : 0;         // cost for bg-distance

    __shared__ int sm[8];                // per-wave (fg,bg) partials

    // ---- prefix phase: fwd[i] = i + min_{j<=i} (cost_j - j) ----
    int a = cf - px, c = cb - px;
    #pragma unroll
    for (int off = 1; off < 64; off <<= 1) {
        const int ua = __shfl_up(a, off, 64);
        const int uc = __shfl_up(c, off, 64);
        if (lane >= off) { a = min(a, ua); c = min(c, uc); }
    }
    if (lane == 63) { sm[wid * 2] = a; sm[wid * 2 + 1] = c; }
    __syncthreads();
    #pragma unroll
    for (int w = 0; w < 3; ++w) {
        if (w < wid) { a = min(a, sm[w * 2]); c = min(c, sm[w * 2 + 1]); }
    }
    const int fwd_fg = px + a;
    const int fwd_bg = px + c;
    __syncthreads();

    // ---- suffix phase: bwd[i] = -i + min_{j>=i} (cost_j + j) ----
    int a2 = cf + px, c2 = cb + px;
    #pragma unroll
    for (int off = 1; off < 64; off <<= 1) {
        const int ua = __shfl_down(a2, off, 64);
        const int uc = __shfl_down(c2, off, 64);
        if (lane + off < 64) { a2 = min(a2, ua); c2 = min(c2, uc); }
    }
    if (lane == 0) { sm[wid * 2] = a2; sm[wid * 2 + 1] = c2; }
    __syncthreads();
    #pragma unroll
    for (int w = 1; w < 4; ++w) {
        if (w > wid) { a2 = min(a2, sm[w * 2]); c2 = min(c2, sm[w * 2 + 1]); }
    }
    const int bwd_fg = a2 - px;
    const int bwd_bg = c2 - px;

    int rf = min(fwd_fg, bwd_fg); if (rf > 255) rf = RSENT;
    int rb = min(fwd_bg, bwd_bg); if (rb > 255) rb = RSENT;
    d1[b * W + px] = make_short2((short)rf, (short)rb);
}

// -------- Kernel 2: windowed column pass (+rare exact fallback) + loss + block reduce --------
__global__ __launch_bounds__(256) void main_pass_kernel(
    const float* __restrict__ pred, const float* __restrict__ tgt,
    const short2* __restrict__ d1, float* __restrict__ parts)
{
    const int blk  = blockIdx.x;             // n*H + py
    const int n    = blk >> 8;
    const int py   = blk & 255;
    const int px   = threadIdx.x;
    const int lane = threadIdx.x & 63;
    const int wid  = threadIdx.x >> 6;
    const int idx  = blk * W + px;

    const float x = pred[idx];
    const float t = tgt[idx];

    const short2* __restrict__ img = d1 + (size_t)n * (H * W) + px;

    // exact column pass: best = min over qy of (qy-py)^2 + r[qy]^2.
    // Preload the +-WIN window (independent loads -> one round trip), then
    // extend outward only if some lane's best could still improve (rare).
    int best_f = INT_MAX, best_b = INT_MAX;
    #pragma unroll
    for (int d = -WIN; d <= WIN; ++d) {
        const int qy = py + d;               // wave-uniform bounds test
        if (qy >= 0 && qy < H) {
            const short2 r = img[qy * W];
            const int d2 = d * d;
            best_f = min(best_f, (int)r.x * (int)r.x + d2);
            best_b = min(best_b, (int)r.y * (int)r.y + d2);
        }
    }
    for (int dlt = WIN + 1; dlt < H; ++dlt) {
        const int d2 = dlt * dlt;
        if (!__any((d2 < best_f) || (d2 < best_b))) break;
        const int up = py - dlt;
        const int dn = py + dlt;
        if (up >= 0) {
            const short2 r = img[up * W];
            best_f = min(best_f, (int)r.x * (int)r.x + d2);
            best_b = min(best_b, (int)r.y * (int)r.y + d2);
        }
        if (dn < H) {
            const short2 r = img[dn * W];
            best_f = min(best_f, (int)r.x * (int)r.x + d2);
            best_b = min(best_b, (int)r.y * (int)r.y + d2);
        }
        if (up < 0 && dn >= H) break;
    }

    const float MAXD2 = (float)((H - 1) * (H - 1) + (W - 1) * (W - 1));
    const float Dfg = (best_f > EMPTY_THRESH) ? MAXD2 : (float)best_f;
    const float Dbg = (best_b > EMPTY_THRESH) ? MAXD2 : (float)best_b;

    const float p   = 1.0f / (1.0f + expf(-x));
    const float phi = (t > 0.5f) ? -sqrtf(Dbg) : sqrtf(Dfg);

    const float pc = fminf(fmaxf(p, FEPS), 1.0f - FEPS);
    const float pt = pc * t + (1.0f - pc) * (1.0f - t);
    const float at = 0.25f * t + 0.75f * (1.0f - t);
    const float om = 1.0f - pt;
    const float focal = -at * om * om * logf(pt);

    // block reduction of the 5 partials
    float v5[5] = { p * t, p, t, phi * p, focal };
    __shared__ float smem[4 * 5];
    #pragma unroll
    for (int q = 0; q < 5; ++q) {
        float v = v5[q];
        #pragma unroll
        for (int off = 32; off > 0; off >>= 1) v += __shfl_down(v, off, 64);
        v5[q] = v;
    }
    if (lane == 0) {
        #pragma unroll
        for (int q = 0; q < 5; ++q) smem[wid * 5 + q] = v5[q];
    }
    __syncthreads();
    if (threadIdx.x == 0) {
        #pragma unroll
        for (int q = 0; q < 5; ++q) {
            parts[q * NBLK2 + blk] = smem[q] + smem[5 + q] + smem[10 + q] + smem[15 + q];
        }
    }
}

// -------- Kernel 3: final reduction to the 4 scalars --------
__global__ __launch_bounds__(256) void finalize_kernel(
    const float* __restrict__ parts, float* __restrict__ out)
{
    const int tid  = threadIdx.x;        // 256 threads
    const int lane = tid & 63;
    const int wid  = tid >> 6;
    __shared__ float smf[8];
    __shared__ float sratio[8];

    // boundary + focal: global sums over all NBLK2 partials
    float bp = 0.0f, fc = 0.0f;
    for (int k = tid; k < NBLK2; k += 256) {
        bp += parts[3 * NBLK2 + k];
        fc += parts[4 * NBLK2 + k];
    }
    #pragma unroll
    for (int off = 32; off > 0; off >>= 1) {
        bp += __shfl_down(bp, off, 64);
        fc += __shfl_down(fc, off, 64);
    }
    if (lane == 0) { smf[wid * 2] = bp; smf[wid * 2 + 1] = fc; }

    // dice: each wave handles 2 images (256 partials each)
    #pragma unroll
    for (int mi = 0; mi < 2; ++mi) {
        const int m = wid * 2 + mi;
        float A = 0.f, S = 0.f, C = 0.f;
        #pragma unroll
        for (int k = 0; k < 4; ++k) {
            const int i = m * 256 + k * 64 + lane;
            A += parts[0 * NBLK2 + i];
            S += parts[1 * NBLK2 + i];
            C += parts[2 * NBLK2 + i];
        }
        #pragma unroll
        for (int off = 32; off > 0; off >>= 1) {
            A += __shfl_down(A, off, 64);
            S += __shfl_down(S, off, 64);
            C += __shfl_down(C, off, 64);
        }
        if (lane == 0) sratio[m] = (2.0f * A + FEPS) / (S + C + FEPS);
    }
    __syncthreads();
    if (tid == 0) {
        const float B = smf[0] + smf[2] + smf[4] + smf[6];
        const float F = smf[1] + smf[3] + smf[5] + smf[7];
        float dacc = 0.0f;
        #pragma unroll
        for (int m = 0; m < 8; ++m) dacc += sratio[m];
        const float dice_val     = 1.0f - dacc / (float)N;
        const float boundary_val = B / (float)NPIX;
        const float focal_val    = F / (float)NPIX;
        out[0] = dice_val + boundary_val + focal_val;   // loss
        out[1] = dice_val;
        out[2] = boundary_val;
        out[3] = focal_val;
    }
}

extern "C" void kernel_launch(void* const* d_in, const int* in_sizes, int n_in,
                              void* d_out, int out_size, void* d_ws, size_t ws_size,
                              hipStream_t stream)
{
    const float* pred = (const float*)d_in[0];
    const float* tgt  = (const float*)d_in[1];
    float* out = (float*)d_out;

    short2* d1    = (short2*)d_ws;                                  // 2 MB
    float*  parts = (float*)((char*)d_ws + (size_t)NPIX * sizeof(short2));

    row_scan_kernel<<<N * H, 256, 0, stream>>>(tgt, d1);
    main_pass_kernel<<<NBLK2, 256, 0, stream>>>(pred, tgt, d1, parts);
    finalize_kernel<<<1, 256, 0, stream>>>(parts, out);
}